// Round 10
// baseline (39.246 us; speedup 1.0000x reference)
//
#include <hip/hip_runtime.h>
#include <hip/hip_bf16.h>
#include <stdint.h>

typedef __attribute__((ext_vector_type(8)))  short    bf16x8;
typedef __attribute__((ext_vector_type(16))) float    f32x16;
typedef __attribute__((ext_vector_type(2)))  float    f32x2;
typedef __attribute__((ext_vector_type(4)))  float    float4v;
typedef __attribute__((ext_vector_type(4)))  unsigned uint4v;
typedef __attribute__((ext_vector_type(2)))  int      int2v;

#define DEVINL static __device__ __forceinline__

#define B_  2
#define H_  8
#define S_  2048
#define D_  64
#define KVB 128
#define NKT (S_ / KVB)

DEVINL unsigned short f2bf(float f) {
  union { float f; unsigned u; } v; v.f = f;
  unsigned r = v.u + 0x7FFFu + ((v.u >> 16) & 1u);   // RNE
  return (unsigned short)(r >> 16);
}

DEVINL unsigned short bfu(float f) {
  __hip_bfloat16 h = __float2bfloat16(f);
  unsigned short u; __builtin_memcpy(&u, &h, 2); return u;
}

DEVINL unsigned pkcvt(float a, float b) {
  return (unsigned)bfu(a) | ((unsigned)bfu(b) << 16);
}

DEVINL void gload_lds16(const void* g, void* l) {
  __builtin_amdgcn_global_load_lds(
      (const __attribute__((address_space(1))) void*)g,
      (__attribute__((address_space(3))) void*)l, 16, 0, 0);
}

DEVINL bf16x8 frag_from_words(unsigned a, unsigned b, unsigned c, unsigned d) {
  union { unsigned u[4]; bf16x8 v; } x;
  x.u[0] = a; x.u[1] = b; x.u[2] = c; x.u[3] = d;
  return x.v;
}

// C-row map for 32x32 MFMA: row = (r&3) + 8*(r>>2) + 4*hi
#define CROW(r, hi) (((r) & 3) + 8 * ((r) >> 2) + 4 * (hi))

// ---------------- prep (R7-proven, unchanged): fragment-ordered bf16 K/V tiles ----------------
__global__ __launch_bounds__(256) void prep_kernel(
    const float* __restrict__ K, const float* __restrict__ V,
    unsigned short* __restrict__ KVf) {
  const int blk = blockIdx.x;        // 64 blocks: (b,kt) x {K,V}
  const int b  = blk >> 5;
  const int kt = (blk >> 1) & 15;
  const int t  = threadIdx.x;
  const int w  = t >> 6, l = t & 63;
  const int lq = l & 31, hi = l >> 5;

  unsigned short* out = KVf + (size_t)(b * 16 + kt) * 16384;

  if ((blk & 1) == 0) {
#pragma unroll
    for (int j = 0; j < 4; ++j) {
      const int fi = w * 4 + j;
      const int kh = fi >> 2, ks = fi & 3;
      const float* src = K + ((size_t)(b * 2048 + kt * 128 + kh * 32 + lq)) * 64 + ks * 16 + hi * 8;
      const float4v x0 = *(const float4v*)(src);
      const float4v x1 = *(const float4v*)(src + 4);
      uint4v o;
      o.x = (unsigned)f2bf(x0.x) | ((unsigned)f2bf(x0.y) << 16);
      o.y = (unsigned)f2bf(x0.z) | ((unsigned)f2bf(x0.w) << 16);
      o.z = (unsigned)f2bf(x1.x) | ((unsigned)f2bf(x1.y) << 16);
      o.w = (unsigned)f2bf(x1.z) | ((unsigned)f2bf(x1.w) << 16);
      *(uint4v*)(out + fi * 512 + l * 8) = o;
    }
  } else {
    __shared__ float Vs[128][65];
#pragma unroll
    for (int rep = 0; rep < 4; ++rep) {
      const int row = rep * 32 + (t >> 3);
      const int col = (t & 7) * 8;
      const float* src = V + ((size_t)(b * 2048 + kt * 128 + row)) * 64 + col;
      const float4v y0 = *(const float4v*)(src);
      const float4v y1 = *(const float4v*)(src + 4);
      Vs[row][col + 0] = y0.x; Vs[row][col + 1] = y0.y;
      Vs[row][col + 2] = y0.z; Vs[row][col + 3] = y0.w;
      Vs[row][col + 4] = y1.x; Vs[row][col + 5] = y1.y;
      Vs[row][col + 6] = y1.z; Vs[row][col + 7] = y1.w;
    }
    __syncthreads();
#pragma unroll
    for (int j = 0; j < 4; ++j) {
      const int fj = w * 4 + j;
      const int kh = fj >> 2, s = (fj >> 1) & 1, nt = fj & 1;
      const int d  = nt * 32 + lq;
      const int k0 = kh * 32 + s * 16 + hi * 8;
      unsigned short o[8];
#pragma unroll
      for (int e = 0; e < 8; ++e) o[e] = f2bf(Vs[k0 + e][d]);
      uint4v wv;
      wv.x = (unsigned)o[0] | ((unsigned)o[1] << 16);
      wv.y = (unsigned)o[2] | ((unsigned)o[3] << 16);
      wv.z = (unsigned)o[4] | ((unsigned)o[5] << 16);
      wv.w = (unsigned)o[6] | ((unsigned)o[7] << 16);
      *(uint4v*)(out + (16 + fj) * 512 + l * 8) = wv;
    }
  }
}

// ---------------- attention: 4 waves, wave-private slices, NO intra-loop barriers ----------------
__global__ __launch_bounds__(256, 2) void attn_kernel(
    const float* __restrict__ Q, const unsigned short* __restrict__ KVf,
    float* __restrict__ O) {
  __shared__ __align__(16) unsigned char smem[65536];   // 2 x 32 KiB tile buffers

  const int bid = blockIdx.x;
  const int b  = bid >> 8;
  const int h  = (bid >> 5) & 7;
  const int qt = bid & 31;

  const int tid  = threadIdx.x;
  const int lane = tid & 63;
  const int kh   = tid >> 6;        // wave = key-quarter (32 keys)
  const int hi   = lane >> 5;
  const int lq   = lane & 31;

  // wave-private slice pointers (8 KiB per tile: K frags kh*4.., V frags 16K + kh*4..)
  const unsigned char* wsrc = (const unsigned char*)KVf
      + (size_t)b * 16 * 32768 + (size_t)kh * 4096 + (size_t)lane * 16;
  unsigned char* wdst = smem + (size_t)kh * 4096 + (size_t)lane * 16;

  // ---- Q B-fragments for BOTH q-groups (scaled by 1/sqrt(D) * log2(e)) ----
  const float qscale = 0.125f * 1.4426950408889634f;
  bf16x8 qfrag0[4], qfrag1[4];
#pragma unroll
  for (int qg = 0; qg < 2; ++qg) {
    const float* qrow = Q + ((size_t)((b * H_ + h) * S_) + (size_t)(qt * 64 + qg * 32 + lq)) * 64;
#pragma unroll
    for (int ks = 0; ks < 4; ++ks) {
      const float* p = qrow + ks * 16 + hi * 8;
      float4v x0 = *(const float4v*)(p);
      float4v x1 = *(const float4v*)(p + 4);
      bf16x8 f;
      f[0] = (short)f2bf(x0.x * qscale); f[1] = (short)f2bf(x0.y * qscale);
      f[2] = (short)f2bf(x0.z * qscale); f[3] = (short)f2bf(x0.w * qscale);
      f[4] = (short)f2bf(x1.x * qscale); f[5] = (short)f2bf(x1.y * qscale);
      f[6] = (short)f2bf(x1.z * qscale); f[7] = (short)f2bf(x1.w * qscale);
      if (qg == 0) qfrag0[ks] = f; else qfrag1[ks] = f;
    }
  }

  f32x16 acc00, acc01, acc10, acc11;
#pragma unroll
  for (int r = 0; r < 16; ++r) { acc00[r] = 0.f; acc01[r] = 0.f; acc10[r] = 0.f; acc11[r] = 0.f; }
  float lrun0 = 0.f, lrun1 = 0.f;

  // wave-private stage: 8 x gload_lds16 (4 K frags + 4 V frags of own slice)
#define STAGE(BUF, KT)                                                             \
  do {                                                                             \
    _Pragma("unroll")                                                              \
    for (int j = 0; j < 4; ++j) {                                                  \
      gload_lds16(wsrc + (size_t)(KT) * 32768 + j * 1024,                          \
                  wdst + (BUF) * 32768 + j * 1024);                                \
      gload_lds16(wsrc + (size_t)(KT) * 32768 + 16384 + j * 1024,                  \
                  wdst + (BUF) * 32768 + 16384 + j * 1024);                        \
    }                                                                              \
  } while (0)

  STAGE(0, 0);

  int buf = 0;
  for (int kt = 0; kt < NKT; ++kt) {
    // own loads for tile kt (issued last iter) must be in LDS; no block barrier.
    asm volatile("s_waitcnt vmcnt(0)" ::: "memory");
    __builtin_amdgcn_sched_barrier(0);

    if (kt + 1 < NKT) STAGE(buf ^ 1, kt + 1);

    // ---- QK^T (swapped) for both q-groups; K frags read once ----
    const unsigned short* Kt = (const unsigned short*)(smem + buf * 32768 + kh * 4096);
    f32x16 c0, c1;
#pragma unroll
    for (int r = 0; r < 16; ++r) { c0[r] = 0.f; c1[r] = 0.f; }
    __builtin_amdgcn_s_setprio(1);
#pragma unroll
    for (int ks = 0; ks < 4; ++ks) {
      const bf16x8 a = *(const bf16x8*)(Kt + ks * 512 + lane * 8);
      c0 = __builtin_amdgcn_mfma_f32_32x32x16_bf16(a, qfrag0[ks], c0, 0, 0, 0);
      c1 = __builtin_amdgcn_mfma_f32_32x32x16_bf16(a, qfrag1[ks], c1, 0, 0, 0);
    }
    __builtin_amdgcn_s_setprio(0);

    // ---- V fragments to registers ----
    const unsigned short* Vt = (const unsigned short*)(smem + buf * 32768 + 16384 + kh * 4096);
    const bf16x8 v0 = *(const bf16x8*)(Vt + 0 * 512 + lane * 8);
    const bf16x8 v1 = *(const bf16x8*)(Vt + 1 * 512 + lane * 8);
    const bf16x8 v2 = *(const bf16x8*)(Vt + 2 * 512 + lane * 8);
    const bf16x8 v3 = *(const bf16x8*)(Vt + 3 * 512 + lane * 8);

    // ---- qg0: P = exp2(sc); lane-partial l; pack; PV ----
#pragma unroll
    for (int r = 0; r < 16; ++r) c0[r] = __builtin_amdgcn_exp2f(c0[r]);
    {
      f32x2 ps = (f32x2){0.f, 0.f};
#pragma unroll
      for (int r = 0; r < 8; ++r) ps += (f32x2){c0[2 * r], c0[2 * r + 1]};
      lrun0 += ps.x + ps.y;
      const unsigned wa0 = pkcvt(c0[0], c0[1]),  wa1 = pkcvt(c0[2], c0[3]);
      const unsigned wa2 = pkcvt(c0[4], c0[5]),  wa3 = pkcvt(c0[6], c0[7]);
      const unsigned wb0 = pkcvt(c0[8], c0[9]),  wb1 = pkcvt(c0[10], c0[11]);
      const unsigned wb2 = pkcvt(c0[12], c0[13]), wb3 = pkcvt(c0[14], c0[15]);
      const int2v a02 = __builtin_amdgcn_permlane32_swap((int)wa0, (int)wa2, false, false);
      const int2v a13 = __builtin_amdgcn_permlane32_swap((int)wa1, (int)wa3, false, false);
      const int2v b02 = __builtin_amdgcn_permlane32_swap((int)wb0, (int)wb2, false, false);
      const int2v b13 = __builtin_amdgcn_permlane32_swap((int)wb1, (int)wb3, false, false);
      const bf16x8 pf0 = frag_from_words((unsigned)a02.x, (unsigned)a13.x,
                                         (unsigned)a02.y, (unsigned)a13.y);
      const bf16x8 pf1 = frag_from_words((unsigned)b02.x, (unsigned)b13.x,
                                         (unsigned)b02.y, (unsigned)b13.y);
      __builtin_amdgcn_s_setprio(1);
      acc00 = __builtin_amdgcn_mfma_f32_32x32x16_bf16(pf0, v0, acc00, 0, 0, 0);
      acc01 = __builtin_amdgcn_mfma_f32_32x32x16_bf16(pf0, v1, acc01, 0, 0, 0);
      acc00 = __builtin_amdgcn_mfma_f32_32x32x16_bf16(pf1, v2, acc00, 0, 0, 0);
      acc01 = __builtin_amdgcn_mfma_f32_32x32x16_bf16(pf1, v3, acc01, 0, 0, 0);
      __builtin_amdgcn_s_setprio(0);
    }

    // ---- qg1 ----
#pragma unroll
    for (int r = 0; r < 16; ++r) c1[r] = __builtin_amdgcn_exp2f(c1[r]);
    {
      f32x2 ps = (f32x2){0.f, 0.f};
#pragma unroll
      for (int r = 0; r < 8; ++r) ps += (f32x2){c1[2 * r], c1[2 * r + 1]};
      lrun1 += ps.x + ps.y;
      const unsigned wa0 = pkcvt(c1[0], c1[1]),  wa1 = pkcvt(c1[2], c1[3]);
      const unsigned wa2 = pkcvt(c1[4], c1[5]),  wa3 = pkcvt(c1[6], c1[7]);
      const unsigned wb0 = pkcvt(c1[8], c1[9]),  wb1 = pkcvt(c1[10], c1[11]);
      const unsigned wb2 = pkcvt(c1[12], c1[13]), wb3 = pkcvt(c1[14], c1[15]);
      const int2v a02 = __builtin_amdgcn_permlane32_swap((int)wa0, (int)wa2, false, false);
      const int2v a13 = __builtin_amdgcn_permlane32_swap((int)wa1, (int)wa3, false, false);
      const int2v b02 = __builtin_amdgcn_permlane32_swap((int)wb0, (int)wb2, false, false);
      const int2v b13 = __builtin_amdgcn_permlane32_swap((int)wb1, (int)wb3, false, false);
      const bf16x8 pf0 = frag_from_words((unsigned)a02.x, (unsigned)a13.x,
                                         (unsigned)a02.y, (unsigned)a13.y);
      const bf16x8 pf1 = frag_from_words((unsigned)b02.x, (unsigned)b13.x,
                                         (unsigned)b02.y, (unsigned)b13.y);
      __builtin_amdgcn_s_setprio(1);
      acc10 = __builtin_amdgcn_mfma_f32_32x32x16_bf16(pf0, v0, acc10, 0, 0, 0);
      acc11 = __builtin_amdgcn_mfma_f32_32x32x16_bf16(pf0, v1, acc11, 0, 0, 0);
      acc10 = __builtin_amdgcn_mfma_f32_32x32x16_bf16(pf1, v2, acc10, 0, 0, 0);
      acc11 = __builtin_amdgcn_mfma_f32_32x32x16_bf16(pf1, v3, acc11, 0, 0, 0);
      __builtin_amdgcn_s_setprio(0);
    }

    buf ^= 1;
  }

  // ---- combine across 4 kh waves via LDS (scale factors 1; only l and O partials) ----
  const float lfull0 = lrun0 + __shfl_xor(lrun0, 32);
  const float lfull1 = lrun1 + __shfl_xor(lrun1, 32);
  __syncthreads();                    // all waves done with K/V LDS
  float* Lb = (float*)smem;           // [2 qg][4 kh][32]
  float* Ab = Lb + 256;               // [3 kh][2 qg][32][64] partial O (48 KiB)
  if (lane < 32) {
    Lb[(0 * 4 + kh) * 32 + lane] = lfull0;
    Lb[(1 * 4 + kh) * 32 + lane] = lfull1;
  }
  if (kh > 0) {
    float* dst = Ab + (size_t)((kh - 1) * 2) * 2048;
#pragma unroll
    for (int r = 0; r < 16; ++r) {
      const int row = CROW(r, hi);
      dst[row * 64 + lq]             = acc00[r];
      dst[row * 64 + 32 + lq]        = acc01[r];
      dst[2048 + row * 64 + lq]      = acc10[r];
      dst[2048 + row * 64 + 32 + lq] = acc11[r];
    }
  }
  __syncthreads();
  if (kh == 0) {
    const float lt0 = Lb[(0 * 4 + 0) * 32 + lq] + Lb[(0 * 4 + 1) * 32 + lq]
                    + Lb[(0 * 4 + 2) * 32 + lq] + Lb[(0 * 4 + 3) * 32 + lq];
    const float lt1 = Lb[(1 * 4 + 0) * 32 + lq] + Lb[(1 * 4 + 1) * 32 + lq]
                    + Lb[(1 * 4 + 2) * 32 + lq] + Lb[(1 * 4 + 3) * 32 + lq];
    const float li0 = 1.f / lt0, li1 = 1.f / lt1;
    float* ob0 = O + ((size_t)((b * H_ + h) * S_) + (size_t)(qt * 64)) * 64;
    float* ob1 = ob0 + (size_t)32 * 64;
#pragma unroll
    for (int r = 0; r < 16; ++r) {
      const int row = CROW(r, hi);
      const float iv0 = __shfl(li0, row);
      const float iv1 = __shfl(li1, row);
      const float* A0 = Ab + row * 64;
      ob0[(size_t)row * 64 + lq] =
          (acc00[r] + A0[lq] + A0[2 * 2048 + lq] + A0[4 * 2048 + lq]) * iv0;
      ob0[(size_t)row * 64 + 32 + lq] =
          (acc01[r] + A0[32 + lq] + A0[2 * 2048 + 32 + lq] + A0[4 * 2048 + 32 + lq]) * iv0;
      const float* A1 = A0 + 2048;
      ob1[(size_t)row * 64 + lq] =
          (acc10[r] + A1[lq] + A1[2 * 2048 + lq] + A1[4 * 2048 + lq]) * iv1;
      ob1[(size_t)row * 64 + 32 + lq] =
          (acc11[r] + A1[32 + lq] + A1[2 * 2048 + 32 + lq] + A1[4 * 2048 + 32 + lq]) * iv1;
    }
  }
}

extern "C" void kernel_launch(void* const* d_in, const int* in_sizes, int n_in,
                              void* d_out, int out_size, void* d_ws, size_t ws_size,
                              hipStream_t stream) {
  const float* Q = (const float*)d_in[0];
  const float* K = (const float*)d_in[1];
  const float* V = (const float*)d_in[2];
  float* O = (float*)d_out;

  unsigned short* KVf = (unsigned short*)d_ws;     // 2 x 16 x 32 KiB = 1 MiB

  prep_kernel<<<64, 256, 0, stream>>>(K, V, KVf);
  attn_kernel<<<B_ * H_ * (S_ / 64), 256, 0, stream>>>(Q, KVf, O);
}